// Round 1
// baseline (670.949 us; speedup 1.0000x reference)
//
#include <hip/hip_runtime.h>
#include <cstdint>
#include <cstddef>

#define NTOK 4096           // B*S
#define DIM  1024           // D
#define HDIM 2048           // H
#define NE   8              // experts
#define BM   128            // GEMM row tile
#define MAXROWS (2*NTOK + NE*BM)   // 9216 worst-case padded slots
#define MBLK (MAXROWS/BM)          // 72 m-blocks (fixed grid)

typedef __attribute__((ext_vector_type(8))) short short8;
typedef __attribute__((ext_vector_type(4))) float f32x4;
typedef __attribute__((ext_vector_type(4))) unsigned short u16x4;

__device__ __forceinline__ unsigned short f2bf(float f) {
    union { float f; unsigned int u; } v; v.f = f;
    return (unsigned short)((v.u + 0x7FFFu + ((v.u >> 16) & 1u)) >> 16);
}

__device__ __forceinline__ void load_lds16(const void* g, void* l) {
    __builtin_amdgcn_global_load_lds(
        (const __attribute__((address_space(1))) void*)(uintptr_t)g,
        (__attribute__((address_space(3))) void*)(uintptr_t)l, 16, 0, 0);
}

// hdr layout (ints): [0..7] counts, [8..15] cursors, [16..24] padded offsets (off[8]=padded_total), [25] aux (float)
__global__ void init_kernel(int* hdr) {
    if (threadIdx.x < 32) hdr[threadIdx.x] = 0;
}

__global__ __launch_bounds__(256) void gate_kernel(
    const float* __restrict__ x, const float* __restrict__ gw, const float* __restrict__ gb,
    float* __restrict__ scores, int* __restrict__ eidx, int* __restrict__ hdr, float* __restrict__ aux)
{
    const int tid = threadIdx.x, lane = tid & 63, wv = tid >> 6;
    const int n = blockIdx.x * 4 + wv;
    float a[NE] = {0.f,0.f,0.f,0.f,0.f,0.f,0.f,0.f};
    const float* xr = x + (size_t)n * DIM;
    for (int d0 = lane * 4; d0 < DIM; d0 += 256) {
        const float4 xv = *reinterpret_cast<const float4*>(xr + d0);
        const float* g = gw + (size_t)d0 * NE;
        const float xs[4] = {xv.x, xv.y, xv.z, xv.w};
        #pragma unroll
        for (int j = 0; j < 4; ++j)
            #pragma unroll
            for (int e = 0; e < NE; ++e)
                a[e] = fmaf(xs[j], g[j*NE + e], a[e]);
    }
    #pragma unroll
    for (int e = 0; e < NE; ++e)
        #pragma unroll
        for (int off = 32; off > 0; off >>= 1)
            a[e] += __shfl_xor(a[e], off);
    if (lane == 0) {
        float lg[NE], slg = 0.f, mx = -1e30f;
        #pragma unroll
        for (int e = 0; e < NE; ++e) { lg[e] = a[e] + gb[e]; slg += lg[e]; mx = fmaxf(mx, lg[e]); }
        float se = 0.f;
        #pragma unroll
        for (int e = 0; e < NE; ++e) se += expf(lg[e] - mx);
        const float lz = mx + logf(se);
        int i0 = 0;
        #pragma unroll
        for (int e = 1; e < NE; ++e) if (lg[e] > lg[i0]) i0 = e;
        int i1 = (i0 == 0) ? 1 : 0;
        #pragma unroll
        for (int e = 0; e < NE; ++e) if (e != i0 && lg[e] > lg[i1]) i1 = e;
        const float ex = expf(lg[i1] - lg[i0]);
        const float p0 = 1.f / (1.f + ex);
        scores[2*n]   = p0;
        scores[2*n+1] = ex * p0;
        eidx[2*n]   = i0;
        eidx[2*n+1] = i1;
        atomicAdd(&hdr[i0], 1);
        atomicAdd(&hdr[i1], 1);
        atomicAdd(aux, slg - 8.f * lz);   // sum_e logp_e for this token
    }
}

__global__ void offsets_kernel(int* hdr) {
    if (threadIdx.x == 0) {
        int off = 0;
        for (int e = 0; e < NE; ++e) {
            hdr[16 + e] = off;
            off += (hdr[e] + BM - 1) & ~(BM - 1);
        }
        hdr[16 + NE] = off;   // padded_total
    }
}

__global__ __launch_bounds__(256) void place_kernel(
    const float* __restrict__ x, const int* __restrict__ eidx,
    int* __restrict__ hdr, int* __restrict__ slot_of, unsigned short* __restrict__ xg)
{
    const int tid = threadIdx.x, lane = tid & 63, wv = tid >> 6;
    const int pair = blockIdx.x * 4 + wv;        // pair = n*2 + k
    const int n = pair >> 1;
    int slot = 0;
    if (lane == 0) {
        const int e = eidx[pair];
        const int pos = atomicAdd(&hdr[8 + e], 1);
        slot = hdr[16 + e] + pos;
        slot_of[pair] = slot;
    }
    slot = __shfl(slot, 0);
    const float* xr = x + (size_t)n * DIM;
    unsigned short* dst = xg + (size_t)slot * DIM;
    for (int d0 = lane * 4; d0 < DIM; d0 += 256) {
        const float4 xv = *reinterpret_cast<const float4*>(xr + d0);
        u16x4 o = { f2bf(xv.x), f2bf(xv.y), f2bf(xv.z), f2bf(xv.w) };
        *reinterpret_cast<u16x4*>(dst + d0) = o;
    }
}

__global__ __launch_bounds__(256) void zeropad_kernel(const int* __restrict__ hdr,
                                                      unsigned short* __restrict__ xg)
{
    const int e = blockIdx.x >> 7, j = blockIdx.x & 127;
    const int cnt = hdr[e];
    const int npad = (hdr[16 + e + 1] - hdr[16 + e]) - cnt;
    if (j >= npad) return;
    unsigned short* row = xg + (size_t)(hdr[16 + e] + cnt + j) * DIM;
    u16x4 z = {0,0,0,0};
    *reinterpret_cast<u16x4*>(row + threadIdx.x * 4) = z;
}

// in: [E][R][C] f32  ->  out: [E][C][R] bf16   (gives weights in [N][K] for contiguous-K frags)
__global__ __launch_bounds__(256) void transpose_kernel(
    const float* __restrict__ in, unsigned short* __restrict__ out, int R, int C)
{
    __shared__ float tile[32][33];
    const int e = blockIdx.z;
    in  += (size_t)e * R * C;
    out += (size_t)e * R * C;
    const int c0 = blockIdx.x * 32, r0 = blockIdx.y * 32;
    const int tx = threadIdx.x, ty = threadIdx.y;
    #pragma unroll
    for (int j = 0; j < 4; ++j)
        tile[ty + 8*j][tx] = in[(size_t)(r0 + ty + 8*j) * C + c0 + tx];
    __syncthreads();
    #pragma unroll
    for (int j = 0; j < 4; ++j)
        out[(size_t)(c0 + ty + 8*j) * R + r0 + tx] = f2bf(tile[tx][ty + 8*j]);
}

// C[row][n] = (GELU? gelu : id)(A[row][:] @ B_e[:][n]);  A:[rows][KD] bf16, Bt:[E][ND][KD] bf16
// GELU=true -> bf16 out; GELU=false -> f32 out
template<int KD, int ND, bool GELU>
__global__ __launch_bounds__(256, 2) void gemm_kernel(
    const unsigned short* __restrict__ A, const unsigned short* __restrict__ Bt,
    void* __restrict__ Cout, const int* __restrict__ hdr)
{
    const int tid = threadIdx.x, lane = tid & 63, wv = tid >> 6;
    const int wr = wv >> 1, wc = wv & 1;
    const int row0 = blockIdx.y * BM;
    if (row0 >= hdr[16 + NE]) return;          // beyond padded_total
    int e = 0;
    while (e < NE - 1 && hdr[16 + e + 1] <= row0) ++e;
    const unsigned short* Be = Bt + (size_t)e * KD * ND;
    const int n0 = blockIdx.x * 128;

    __shared__ __align__(16) unsigned short As[128 * 32];
    __shared__ __align__(16) unsigned short Bs[128 * 32];

    f32x4 acc[4][4] = {};
    const int srow = lane >> 2, scol = (lane & 3) * 8;   // staging lane map
    const int r = lane & 15, hseg = (lane >> 4) * 8;     // fragment lane map

    for (int k0 = 0; k0 < KD; k0 += 32) {
        #pragma unroll
        for (int c = 0; c < 2; ++c) {
            const int ch = wv * 2 + c;                    // wave-uniform chunk id
            const int row = ch * 16 + srow;
            load_lds16(A  + (size_t)(row0 + row) * KD + k0 + scol, As + ch * 512);
            load_lds16(Be + (size_t)(n0  + row) * KD + k0 + scol, Bs + ch * 512);
        }
        __syncthreads();
        short8 af[4], bfr[4];
        #pragma unroll
        for (int m = 0; m < 4; ++m)
            af[m] = *reinterpret_cast<const short8*>(As + (wr*64 + m*16 + r) * 32 + hseg);
        #pragma unroll
        for (int nn = 0; nn < 4; ++nn)
            bfr[nn] = *reinterpret_cast<const short8*>(Bs + (wc*64 + nn*16 + r) * 32 + hseg);
        #pragma unroll
        for (int m = 0; m < 4; ++m)
            #pragma unroll
            for (int nn = 0; nn < 4; ++nn)
                acc[m][nn] = __builtin_amdgcn_mfma_f32_16x16x32_bf16(af[m], bfr[nn], acc[m][nn], 0, 0, 0);
        __syncthreads();
    }

    const int col = lane & 15, rb = (lane >> 4) * 4;      // C/D: col=lane&15, row=(lane>>4)*4+j
    #pragma unroll
    for (int m = 0; m < 4; ++m)
        #pragma unroll
        for (int nn = 0; nn < 4; ++nn)
            #pragma unroll
            for (int j = 0; j < 4; ++j) {
                const int grow = row0 + wr*64 + m*16 + rb + j;
                const int gcol = n0  + wc*64 + nn*16 + col;
                float v = acc[m][nn][j];
                if (GELU) {
                    v = 0.5f * v * (1.0f + erff(v * 0.70710678118654752f));
                    ((unsigned short*)Cout)[(size_t)grow * ND + gcol] = f2bf(v);
                } else {
                    ((float*)Cout)[(size_t)grow * ND + gcol] = v;
                }
            }
}

__global__ __launch_bounds__(256) void combine_kernel(
    const float* __restrict__ sout, const float* __restrict__ scores,
    const int* __restrict__ slot_of, float* __restrict__ out)
{
    const int n = blockIdx.x;
    const float s0 = scores[2*n], s1 = scores[2*n+1];
    const int sa = slot_of[2*n], sb = slot_of[2*n+1];
    const int d = threadIdx.x * 4;
    const float4 va = *reinterpret_cast<const float4*>(sout + (size_t)sa * DIM + d);
    const float4 vb = *reinterpret_cast<const float4*>(sout + (size_t)sb * DIM + d);
    float4 o;
    o.x = s0*va.x + s1*vb.x; o.y = s0*va.y + s1*vb.y;
    o.z = s0*va.z + s1*vb.z; o.w = s0*va.w + s1*vb.w;
    *reinterpret_cast<float4*>(out + (size_t)n * DIM + d) = o;
}

__global__ void aux_kernel(const float* __restrict__ aux, float* __restrict__ out) {
    if (threadIdx.x == 0) {
        const float t = 0.125f;
        out[(size_t)NTOK * DIM] = 0.01f * t * (logf(t) - aux[0] / (float)(NTOK * NE));
    }
}

// ---- workspace layout (bytes) ----
constexpr size_t OFF_SCORES = 1024;
constexpr size_t OFF_IDX    = OFF_SCORES + (size_t)NTOK * 2 * 4;
constexpr size_t OFF_SLOT   = OFF_IDX    + (size_t)NTOK * 2 * 4;
constexpr size_t OFF_XG     = 131072;
constexpr size_t OFF_W1T    = OFF_XG  + (size_t)MAXROWS * DIM  * 2;
constexpr size_t OFF_W2T    = OFF_W1T + (size_t)NE * DIM * HDIM * 2;
constexpr size_t OFF_H      = OFF_W2T + (size_t)NE * DIM * HDIM * 2;
constexpr size_t OFF_SOUT   = OFF_H   + (size_t)MAXROWS * HDIM * 2;
constexpr size_t WS_NEED    = OFF_SOUT + (size_t)MAXROWS * DIM  * 4;

extern "C" void kernel_launch(void* const* d_in, const int* in_sizes, int n_in,
                              void* d_out, int out_size, void* d_ws, size_t ws_size,
                              hipStream_t stream) {
    const float* x  = (const float*)d_in[0];
    const float* gw = (const float*)d_in[1];
    const float* gb = (const float*)d_in[2];
    const float* w1 = (const float*)d_in[3];
    const float* w2 = (const float*)d_in[4];
    float* out = (float*)d_out;

    if (ws_size < WS_NEED) return;   // fail loudly (output stays poisoned)

    char* ws = (char*)d_ws;
    int*   hdr     = (int*)ws;
    float* aux     = (float*)(ws + 25 * 4);
    float* scores  = (float*)(ws + OFF_SCORES);
    int*   eidx    = (int*)(ws + OFF_IDX);
    int*   slot_of = (int*)(ws + OFF_SLOT);
    unsigned short* xg  = (unsigned short*)(ws + OFF_XG);
    unsigned short* w1t = (unsigned short*)(ws + OFF_W1T);
    unsigned short* w2t = (unsigned short*)(ws + OFF_W2T);
    unsigned short* h   = (unsigned short*)(ws + OFF_H);
    float* sout         = (float*)(ws + OFF_SOUT);

    init_kernel<<<1, 64, 0, stream>>>(hdr);
    transpose_kernel<<<dim3(HDIM/32, DIM/32, NE), dim3(32, 8), 0, stream>>>(w1, w1t, DIM, HDIM);
    transpose_kernel<<<dim3(DIM/32, HDIM/32, NE), dim3(32, 8), 0, stream>>>(w2, w2t, HDIM, DIM);
    gate_kernel<<<NTOK/4, 256, 0, stream>>>(x, gw, gb, scores, eidx, hdr, aux);
    offsets_kernel<<<1, 64, 0, stream>>>(hdr);
    place_kernel<<<2*NTOK/4, 256, 0, stream>>>(x, eidx, hdr, slot_of, xg);
    zeropad_kernel<<<NE*BM, 256, 0, stream>>>(hdr, xg);
    gemm_kernel<DIM, HDIM, true ><<<dim3(HDIM/128, MBLK), 256, 0, stream>>>(xg, w1t, (void*)h, hdr);
    gemm_kernel<HDIM, DIM, false><<<dim3(DIM/128, MBLK), 256, 0, stream>>>(h, w2t, (void*)sout, hdr);
    combine_kernel<<<NTOK, 256, 0, stream>>>(sout, scores, slot_of, out);
    aux_kernel<<<1, 64, 0, stream>>>(aux, out);
}

// Round 2
// 310.166 us; speedup vs baseline: 2.1632x; 2.1632x over previous
//
#include <hip/hip_runtime.h>
#include <cstdint>
#include <cstddef>

#define NTOK 4096           // B*S
#define DIM  1024           // D
#define HDIM 2048           // H
#define NE   8              // experts
#define BM   128            // GEMM row tile
#define MAXROWS (2*NTOK + NE*BM)   // 9216 worst-case padded slots
#define MBLK (MAXROWS/BM)          // 72 m-blocks (fixed grid)

typedef __attribute__((ext_vector_type(8))) short short8;
typedef __attribute__((ext_vector_type(4))) float f32x4;
typedef __attribute__((ext_vector_type(4))) unsigned short u16x4;

__device__ __forceinline__ unsigned short f2bf(float f) {
    union { float f; unsigned int u; } v; v.f = f;
    return (unsigned short)((v.u + 0x7FFFu + ((v.u >> 16) & 1u)) >> 16);
}

__device__ __forceinline__ void load_lds16(const void* g, void* l) {
    __builtin_amdgcn_global_load_lds(
        (const __attribute__((address_space(1))) void*)(uintptr_t)g,
        (__attribute__((address_space(3))) void*)(uintptr_t)l, 16, 0, 0);
}

// hdr layout (ints): [0..7] counts, [16..24] padded offsets (off[8]=padded_total),
//                    [32 + 16*e] cursors (one per 64B cacheline), [25] aux handled separately
__global__ void init_kernel(int* hdr) {
    hdr[threadIdx.x] = 0;   // 256 ints
}

__global__ __launch_bounds__(256) void gate_kernel(
    const float* __restrict__ x, const float* __restrict__ gw, const float* __restrict__ gb,
    float* __restrict__ scores, int* __restrict__ eidx, int* __restrict__ hdr, float* __restrict__ aux)
{
    const int tid = threadIdx.x, lane = tid & 63, wv = tid >> 6;
    const int n = blockIdx.x * 4 + wv;
    float a[NE] = {0.f,0.f,0.f,0.f,0.f,0.f,0.f,0.f};
    const float* xr = x + (size_t)n * DIM;
    for (int d0 = lane * 4; d0 < DIM; d0 += 256) {
        const float4 xv = *reinterpret_cast<const float4*>(xr + d0);
        const float* g = gw + (size_t)d0 * NE;
        const float xs[4] = {xv.x, xv.y, xv.z, xv.w};
        #pragma unroll
        for (int j = 0; j < 4; ++j)
            #pragma unroll
            for (int e = 0; e < NE; ++e)
                a[e] = fmaf(xs[j], g[j*NE + e], a[e]);
    }
    #pragma unroll
    for (int e = 0; e < NE; ++e)
        #pragma unroll
        for (int off = 32; off > 0; off >>= 1)
            a[e] += __shfl_xor(a[e], off);
    if (lane == 0) {
        float lg[NE], slg = 0.f, mx = -1e30f;
        #pragma unroll
        for (int e = 0; e < NE; ++e) { lg[e] = a[e] + gb[e]; slg += lg[e]; mx = fmaxf(mx, lg[e]); }
        float se = 0.f;
        #pragma unroll
        for (int e = 0; e < NE; ++e) se += expf(lg[e] - mx);
        const float lz = mx + logf(se);
        int i0 = 0;
        #pragma unroll
        for (int e = 1; e < NE; ++e) if (lg[e] > lg[i0]) i0 = e;
        int i1 = (i0 == 0) ? 1 : 0;
        #pragma unroll
        for (int e = 0; e < NE; ++e) if (e != i0 && lg[e] > lg[i1]) i1 = e;
        const float ex = expf(lg[i1] - lg[i0]);
        const float p0 = 1.f / (1.f + ex);
        scores[2*n]   = p0;
        scores[2*n+1] = ex * p0;
        eidx[2*n]   = i0;
        eidx[2*n+1] = i1;
        atomicAdd(&hdr[i0], 1);               // non-returning: pipelined
        atomicAdd(&hdr[i1], 1);
        atomicAdd(aux, slg - 8.f * lz);       // sum_e logp_e for this token
    }
}

__global__ void offsets_kernel(int* hdr) {
    if (threadIdx.x == 0) {
        int off = 0;
        for (int e = 0; e < NE; ++e) {
            hdr[16 + e] = off;
            off += (hdr[e] + BM - 1) & ~(BM - 1);
        }
        hdr[16 + NE] = off;   // padded_total
    }
}

// Block-aggregated slot assignment: 256 pairs/block, 8 returning atomics/block.
__global__ __launch_bounds__(256) void assign_kernel(
    const int* __restrict__ eidx, int* __restrict__ hdr, int* __restrict__ slot_of)
{
    __shared__ int cnt[NE];
    __shared__ int base[NE];
    const int tid = threadIdx.x;
    const int p = blockIdx.x * 256 + tid;
    if (tid < NE) cnt[tid] = 0;
    __syncthreads();
    const int e = eidx[p];
    const int pos = atomicAdd(&cnt[e], 1);          // LDS atomic: fast
    __syncthreads();
    if (tid < NE) base[tid] = atomicAdd(&hdr[32 + 16 * tid], cnt[tid]);  // own cacheline
    __syncthreads();
    slot_of[p] = hdr[16 + e] + base[e] + pos;
}

// Atomic-free gather/cast: one wave per pair.
__global__ __launch_bounds__(256) void gather_kernel(
    const float* __restrict__ x, const int* __restrict__ slot_of, unsigned short* __restrict__ xg)
{
    const int tid = threadIdx.x, lane = tid & 63, wv = tid >> 6;
    const int pair = blockIdx.x * 4 + wv;        // pair = n*2 + k
    const int n = pair >> 1;
    const int slot = slot_of[pair];
    const float* xr = x + (size_t)n * DIM;
    unsigned short* dst = xg + (size_t)slot * DIM;
    for (int d0 = lane * 4; d0 < DIM; d0 += 256) {
        const float4 xv = *reinterpret_cast<const float4*>(xr + d0);
        u16x4 o = { f2bf(xv.x), f2bf(xv.y), f2bf(xv.z), f2bf(xv.w) };
        *reinterpret_cast<u16x4*>(dst + d0) = o;
    }
}

__global__ __launch_bounds__(256) void zeropad_kernel(const int* __restrict__ hdr,
                                                      unsigned short* __restrict__ xg)
{
    const int e = blockIdx.x >> 7, j = blockIdx.x & 127;
    const int cnt = hdr[e];
    const int npad = (hdr[16 + e + 1] - hdr[16 + e]) - cnt;
    if (j >= npad) return;
    unsigned short* row = xg + (size_t)(hdr[16 + e] + cnt + j) * DIM;
    u16x4 z = {0,0,0,0};
    *reinterpret_cast<u16x4*>(row + threadIdx.x * 4) = z;
}

// in: [E][R][C] f32  ->  out: [E][C][R] bf16   (gives weights in [N][K] for contiguous-K frags)
__global__ __launch_bounds__(256) void transpose_kernel(
    const float* __restrict__ in, unsigned short* __restrict__ out, int R, int C)
{
    __shared__ float tile[32][33];
    const int e = blockIdx.z;
    in  += (size_t)e * R * C;
    out += (size_t)e * R * C;
    const int c0 = blockIdx.x * 32, r0 = blockIdx.y * 32;
    const int tx = threadIdx.x, ty = threadIdx.y;
    #pragma unroll
    for (int j = 0; j < 4; ++j)
        tile[ty + 8*j][tx] = in[(size_t)(r0 + ty + 8*j) * C + c0 + tx];
    __syncthreads();
    #pragma unroll
    for (int j = 0; j < 4; ++j)
        out[(size_t)(c0 + ty + 8*j) * R + r0 + tx] = f2bf(tile[tx][ty + 8*j]);
}

// C[row][n] = (GELU? gelu : id)(A[row][:] @ B_e[:][n]);  A:[rows][KD] bf16, Bt:[E][ND][KD] bf16
template<int KD, int ND, bool GELU>
__global__ __launch_bounds__(256, 2) void gemm_kernel(
    const unsigned short* __restrict__ A, const unsigned short* __restrict__ Bt,
    void* __restrict__ Cout, const int* __restrict__ hdr)
{
    const int tid = threadIdx.x, lane = tid & 63, wv = tid >> 6;
    const int wr = wv >> 1, wc = wv & 1;
    const int row0 = blockIdx.y * BM;
    if (row0 >= hdr[16 + NE]) return;          // beyond padded_total
    int e = 0;
    while (e < NE - 1 && hdr[16 + e + 1] <= row0) ++e;
    const unsigned short* Be = Bt + (size_t)e * KD * ND;
    const int n0 = blockIdx.x * 128;

    __shared__ __align__(16) unsigned short As[128 * 32];
    __shared__ __align__(16) unsigned short Bs[128 * 32];

    f32x4 acc[4][4] = {};
    const int srow = lane >> 2, scol = (lane & 3) * 8;   // staging lane map
    const int r = lane & 15, hseg = (lane >> 4) * 8;     // fragment lane map

    for (int k0 = 0; k0 < KD; k0 += 32) {
        #pragma unroll
        for (int c = 0; c < 2; ++c) {
            const int ch = wv * 2 + c;                    // wave-uniform chunk id
            const int row = ch * 16 + srow;
            load_lds16(A  + (size_t)(row0 + row) * KD + k0 + scol, As + ch * 512);
            load_lds16(Be + (size_t)(n0  + row) * KD + k0 + scol, Bs + ch * 512);
        }
        __syncthreads();
        short8 af[4], bfr[4];
        #pragma unroll
        for (int m = 0; m < 4; ++m)
            af[m] = *reinterpret_cast<const short8*>(As + (wr*64 + m*16 + r) * 32 + hseg);
        #pragma unroll
        for (int nn = 0; nn < 4; ++nn)
            bfr[nn] = *reinterpret_cast<const short8*>(Bs + (wc*64 + nn*16 + r) * 32 + hseg);
        #pragma unroll
        for (int m = 0; m < 4; ++m)
            #pragma unroll
            for (int nn = 0; nn < 4; ++nn)
                acc[m][nn] = __builtin_amdgcn_mfma_f32_16x16x32_bf16(af[m], bfr[nn], acc[m][nn], 0, 0, 0);
        __syncthreads();
    }

    const int col = lane & 15, rb = (lane >> 4) * 4;      // C/D: col=lane&15, row=(lane>>4)*4+j
    #pragma unroll
    for (int m = 0; m < 4; ++m)
        #pragma unroll
        for (int nn = 0; nn < 4; ++nn)
            #pragma unroll
            for (int j = 0; j < 4; ++j) {
                const int grow = row0 + wr*64 + m*16 + rb + j;
                const int gcol = n0  + wc*64 + nn*16 + col;
                float v = acc[m][nn][j];
                if (GELU) {
                    v = 0.5f * v * (1.0f + erff(v * 0.70710678118654752f));
                    ((unsigned short*)Cout)[(size_t)grow * ND + gcol] = f2bf(v);
                } else {
                    ((float*)Cout)[(size_t)grow * ND + gcol] = v;
                }
            }
}

__global__ __launch_bounds__(256) void combine_kernel(
    const float* __restrict__ sout, const float* __restrict__ scores,
    const int* __restrict__ slot_of, float* __restrict__ out)
{
    const int n = blockIdx.x;
    const float s0 = scores[2*n], s1 = scores[2*n+1];
    const int sa = slot_of[2*n], sb = slot_of[2*n+1];
    const int d = threadIdx.x * 4;
    const float4 va = *reinterpret_cast<const float4*>(sout + (size_t)sa * DIM + d);
    const float4 vb = *reinterpret_cast<const float4*>(sout + (size_t)sb * DIM + d);
    float4 o;
    o.x = s0*va.x + s1*vb.x; o.y = s0*va.y + s1*vb.y;
    o.z = s0*va.z + s1*vb.z; o.w = s0*va.w + s1*vb.w;
    *reinterpret_cast<float4*>(out + (size_t)n * DIM + d) = o;
}

__global__ void aux_kernel(const float* __restrict__ aux, float* __restrict__ out) {
    if (threadIdx.x == 0) {
        const float t = 0.125f;
        out[(size_t)NTOK * DIM] = 0.01f * t * (logf(t) - aux[0] / (float)(NTOK * NE));
    }
}

// ---- workspace layout (bytes) ----
constexpr size_t OFF_AUX    = 1024 + 512;
constexpr size_t OFF_SCORES = 2048;
constexpr size_t OFF_IDX    = OFF_SCORES + (size_t)NTOK * 2 * 4;
constexpr size_t OFF_SLOT   = OFF_IDX    + (size_t)NTOK * 2 * 4;
constexpr size_t OFF_XG     = 131072;
constexpr size_t OFF_W1T    = OFF_XG  + (size_t)MAXROWS * DIM  * 2;
constexpr size_t OFF_W2T    = OFF_W1T + (size_t)NE * DIM * HDIM * 2;
constexpr size_t OFF_H      = OFF_W2T + (size_t)NE * DIM * HDIM * 2;
constexpr size_t OFF_SOUT   = OFF_H   + (size_t)MAXROWS * HDIM * 2;
constexpr size_t WS_NEED    = OFF_SOUT + (size_t)MAXROWS * DIM  * 4;

extern "C" void kernel_launch(void* const* d_in, const int* in_sizes, int n_in,
                              void* d_out, int out_size, void* d_ws, size_t ws_size,
                              hipStream_t stream) {
    const float* x  = (const float*)d_in[0];
    const float* gw = (const float*)d_in[1];
    const float* gb = (const float*)d_in[2];
    const float* w1 = (const float*)d_in[3];
    const float* w2 = (const float*)d_in[4];
    float* out = (float*)d_out;

    if (ws_size < WS_NEED) return;   // fail loudly (output stays poisoned)

    char* ws = (char*)d_ws;
    int*   hdr     = (int*)ws;
    float* aux     = (float*)(ws + OFF_AUX);
    float* scores  = (float*)(ws + OFF_SCORES);
    int*   eidx    = (int*)(ws + OFF_IDX);
    int*   slot_of = (int*)(ws + OFF_SLOT);
    unsigned short* xg  = (unsigned short*)(ws + OFF_XG);
    unsigned short* w1t = (unsigned short*)(ws + OFF_W1T);
    unsigned short* w2t = (unsigned short*)(ws + OFF_W2T);
    unsigned short* h   = (unsigned short*)(ws + OFF_H);
    float* sout         = (float*)(ws + OFF_SOUT);

    init_kernel<<<1, 256, 0, stream>>>(hdr);
    hipMemsetAsync(aux, 0, 4, stream);
    transpose_kernel<<<dim3(HDIM/32, DIM/32, NE), dim3(32, 8), 0, stream>>>(w1, w1t, DIM, HDIM);
    transpose_kernel<<<dim3(DIM/32, HDIM/32, NE), dim3(32, 8), 0, stream>>>(w2, w2t, HDIM, DIM);
    gate_kernel<<<NTOK/4, 256, 0, stream>>>(x, gw, gb, scores, eidx, hdr, aux);
    offsets_kernel<<<1, 64, 0, stream>>>(hdr);
    assign_kernel<<<2*NTOK/256, 256, 0, stream>>>(eidx, hdr, slot_of);
    gather_kernel<<<2*NTOK/4, 256, 0, stream>>>(x, slot_of, xg);
    zeropad_kernel<<<NE*BM, 256, 0, stream>>>(hdr, xg);
    gemm_kernel<DIM, HDIM, true ><<<dim3(HDIM/128, MBLK), 256, 0, stream>>>(xg, w1t, (void*)h, hdr);
    gemm_kernel<HDIM, DIM, false><<<dim3(DIM/128, MBLK), 256, 0, stream>>>(h, w2t, (void*)sout, hdr);
    combine_kernel<<<NTOK, 256, 0, stream>>>(sout, scores, slot_of, out);
    aux_kernel<<<1, 64, 0, stream>>>(aux, out);
}